// Round 6
// baseline (170.826 us; speedup 1.0000x reference)
//
#include <hip/hip_runtime.h>
#include <hip/hip_bf16.h>
#include <stdint.h>

#define D_MODEL 1024

typedef __attribute__((ext_vector_type(4))) float  f32x4;
typedef __attribute__((ext_vector_type(8))) __bf16 bf16x8;
typedef __attribute__((ext_vector_type(8))) unsigned short u16x8;
typedef __attribute__((ext_vector_type(4))) unsigned short u16x4;

// ---------- helpers ----------

__device__ __forceinline__ unsigned order_map(float x) {
    unsigned u = __float_as_uint(x);
    return (u & 0x80000000u) ? ~u : (u | 0x80000000u);
}
__device__ __forceinline__ float order_unmap(unsigned m) {
    unsigned b = (m & 0x80000000u) ? (m & 0x7fffffffu) : ~m;
    return __uint_as_float(b);
}
__device__ __forceinline__ unsigned short f2bf(float f) {
    unsigned u = __float_as_uint(f);
    u += 0x7fffu + ((u >> 16) & 1u);
    return (unsigned short)(u >> 16);
}

// ---------- prelude kernels (unchanged from R4/R5 — at BW floor) ----------

__global__ void init_u32(unsigned* __restrict__ p, int n) {
    int i = blockIdx.x * blockDim.x + threadIdx.x;
    if (i < n) p[i] = 0u;
}

__global__ void colmax_kernel(const float* __restrict__ src, int rows_per_slab,
                              int cols, unsigned* __restrict__ out_u) {
    int k = blockIdx.x * blockDim.x + threadIdx.x;
    const float* p = src + (size_t)blockIdx.y * rows_per_slab * cols + k;
    float m = -__builtin_inff();
#pragma unroll 4
    for (int r = 0; r < rows_per_slab; ++r)
        m = fmaxf(m, p[(size_t)r * cols]);
    atomicMax(&out_u[k], order_map(m));
}

#define CC_ROWS 16
__global__ __launch_bounds__(256)
void colmax_convert(const float* __restrict__ x,
                    float* __restrict__ partial,
                    unsigned short* __restrict__ xb) {
    int c4 = threadIdx.x * 4;
    size_t base = (size_t)blockIdx.x * CC_ROWS * D_MODEL + c4;
    f32x4 m4 = {-__builtin_inff(), -__builtin_inff(), -__builtin_inff(), -__builtin_inff()};
#pragma unroll 8
    for (int r = 0; r < CC_ROWS; ++r) {
        f32x4 v = *reinterpret_cast<const f32x4*>(&x[base + (size_t)r * D_MODEL]);
        u16x4 o;
#pragma unroll
        for (int e = 0; e < 4; ++e) { m4[e] = fmaxf(m4[e], v[e]); o[e] = f2bf(v[e]); }
        *reinterpret_cast<u16x4*>(&xb[base + (size_t)r * D_MODEL]) = o;
    }
    *reinterpret_cast<f32x4*>(&partial[(size_t)blockIdx.x * D_MODEL + c4]) = m4;
}

__global__ void reduce_partial(const float* __restrict__ partial,
                               unsigned* __restrict__ ma_u) {
    int col  = blockIdx.x * 256 + threadIdx.x;
    int b0   = blockIdx.y * 64;
    float m = -__builtin_inff();
#pragma unroll 8
    for (int i = 0; i < 64; ++i)
        m = fmaxf(m, partial[(size_t)(b0 + i) * D_MODEL + col]);
    atomicMax(&ma_u[col], order_map(m));
}

__global__ void scale_kernel(const unsigned* __restrict__ ma_u,
                             const unsigned* __restrict__ mw_u,
                             float* __restrict__ s) {
    int k = blockIdx.x * blockDim.x + threadIdx.x;
    if (k < D_MODEL) {
        float ma = order_unmap(ma_u[k]);
        float mw = order_unmap(mw_u[k]);
        s[k] = sqrtf(ma) / sqrtf(mw);   // ALPHA = 0.5
    }
}

__global__ void build_w_kernel(const float* __restrict__ W, const float* __restrict__ s,
                               unsigned short* __restrict__ Wp) {
    int j  = blockIdx.x;
    int k4 = threadIdx.x * 4;
    float sj = s[j];
    f32x4 w  = *reinterpret_cast<const f32x4*>(&W[(size_t)j * D_MODEL + k4]);
    f32x4 sk = *reinterpret_cast<const f32x4*>(&s[k4]);
    u16x4 o;
#pragma unroll
    for (int i = 0; i < 4; ++i) o[i] = f2bf(sj * w[i] / sk[i]);
    *reinterpret_cast<u16x4*>(&Wp[(size_t)j * D_MODEL + k4]) = o;
}

// ---------- GEMM: 256x256 tile, 8 waves (2Mx4N), BK=64, 8-phase-style ----------
// Per-wave output 128x64 (8x4 16x16 frags) -> 24-28 ds_read_b128 per 64 MFMA
// (vs 16 per 32 before): LDS demand ~93 B/cyc < 128 B/cyc ceiling.
// Per K-tile: 4 phases {frag ds_reads | prefetch issue | barrier | setprio+16 MFMA | barrier};
// tile t+1 staged into buf[cur^1] during tile t (A in ph0, B in ph1);
// single vmcnt(0)+barrier at tile end (loads issued >=2 phases earlier).
#define GBM 256
#define GBN 256
#define GBK 64
#define GNT (D_MODEL / GBK)   // 16

__global__ __launch_bounds__(512, 2)
void gemm_8ph(const unsigned short* __restrict__ Xb,
              const unsigned short* __restrict__ Wp,
              const float* __restrict__ bias,
              float* __restrict__ out) {
    __shared__ __align__(16) unsigned short As[2][GBM][GBK];   // 64 KB
    __shared__ __align__(16) unsigned short Bs[2][GBN][GBK];   // 64 KB

    // XCD swizzle (grid 512 %8==0, bijective). Col-major decode: consecutive
    // swz on one XCD share the Wp col-panel (512 KB, L2-resident).
    int flat = blockIdx.x;
    int swz  = (flat & 7) * (gridDim.x >> 3) + (flat >> 3);
    const int nRowBlk = 32768 / GBM;   // 128
    int row0 = (swz % nRowBlk) * GBM;
    int col0 = (swz / nRowBlk) * GBN;

    int tid  = threadIdx.x;
    int wave = tid >> 6;
    int lane = tid & 63;
    int wr   = wave >> 2;      // 0..1 : rows wr*128
    int wc   = wave & 3;       // 0..3 : cols wc*64
    int l16  = lane & 15;
    int lq   = lane >> 4;      // 0..3 : k-quarter
    int srow  = lane >> 3;                   // staging: row within 8-row group
    int skoff = ((lane & 7) ^ srow) << 3;    // pre-swizzled source k-offset (elems)

    f32x4 acc[2][2][4][2];
#pragma unroll
    for (int mq = 0; mq < 2; ++mq)
#pragma unroll
        for (int nq = 0; nq < 2; ++nq)
#pragma unroll
            for (int m = 0; m < 4; ++m)
#pragma unroll
                for (int n = 0; n < 2; ++n)
                    acc[mq][nq][m][n] = (f32x4){0.f, 0.f, 0.f, 0.f};

    // stage one K-tile's A (or B): 32 row-groups of 8 rows; wave w does rg=w*4+i.
    auto stageA = [&](int t, int b) {
        int k0 = t * GBK;
#pragma unroll
        for (int i = 0; i < 4; ++i) {
            int rg = wave * 4 + i;
            const unsigned short* g = Xb + (size_t)(row0 + rg * 8 + srow) * D_MODEL + k0 + skoff;
            __builtin_amdgcn_global_load_lds(
                (const __attribute__((address_space(1))) void*)g,
                (__attribute__((address_space(3))) void*)&As[b][rg * 8][0], 16, 0, 0);
        }
    };
    auto stageB = [&](int t, int b) {
        int k0 = t * GBK;
#pragma unroll
        for (int i = 0; i < 4; ++i) {
            int rg = wave * 4 + i;
            const unsigned short* g = Wp + (size_t)(col0 + rg * 8 + srow) * D_MODEL + k0 + skoff;
            __builtin_amdgcn_global_load_lds(
                (const __attribute__((address_space(1))) void*)g,
                (__attribute__((address_space(3))) void*)&Bs[b][rg * 8][0], 16, 0, 0);
        }
    };

    // prologue: tile 0 only (tile t+1 staged during tile t)
    stageA(0, 0); stageB(0, 0);
    asm volatile("s_waitcnt vmcnt(0)" ::: "memory");
    __builtin_amdgcn_s_barrier();

#pragma unroll 1
    for (int t = 0; t < GNT; ++t) {
        int cur = t & 1;
        const char* Ab = (const char*)&As[cur][0][0];
        const char* Bb = (const char*)&Bs[cur][0][0];
        bool pf = (t < GNT - 1);

        bf16x8 af[4][2], bf[2][2];

        auto lda = [&](int mq, int m, int kk) {
            int row  = wr * 128 + mq * 64 + m * 16 + l16;
            int slot = (kk * 4 + lq) ^ (row & 7);
            return *reinterpret_cast<const bf16x8*>(Ab + row * 128 + slot * 16);
        };
        auto ldb = [&](int nq, int n, int kk) {
            int row  = wc * 64 + nq * 32 + n * 16 + l16;
            int slot = (kk * 4 + lq) ^ (row & 7);
            return *reinterpret_cast<const bf16x8*>(Bb + row * 128 + slot * 16);
        };
        auto quad = [&](int mq, int nq) {
            __builtin_amdgcn_s_setprio(1);
#pragma unroll
            for (int m = 0; m < 4; ++m)
#pragma unroll
                for (int n = 0; n < 2; ++n)
#pragma unroll
                    for (int kk = 0; kk < 2; ++kk)
                        acc[mq][nq][m][n] = __builtin_amdgcn_mfma_f32_16x16x32_bf16(
                            af[m][kk], bf[n][kk], acc[mq][nq][m][n], 0, 0, 0);
            __builtin_amdgcn_s_setprio(0);
        };

        // ---- phase 0: quadrant (0,0). Reads: af[0..3] (8), bf nq0 (4). Prefetch A(t+1).
#pragma unroll
        for (int m = 0; m < 4; ++m)
#pragma unroll
            for (int kk = 0; kk < 2; ++kk) af[m][kk] = lda(0, m, kk);
#pragma unroll
        for (int n = 0; n < 2; ++n)
#pragma unroll
            for (int kk = 0; kk < 2; ++kk) bf[n][kk] = ldb(0, n, kk);
        if (pf) stageA(t + 1, cur ^ 1);
        __builtin_amdgcn_s_barrier();
        quad(0, 0);
        __builtin_amdgcn_s_barrier();

        // ---- phase 1: quadrant (0,1). Reads: bf nq1 (4). Prefetch B(t+1).
#pragma unroll
        for (int n = 0; n < 2; ++n)
#pragma unroll
            for (int kk = 0; kk < 2; ++kk) bf[n][kk] = ldb(1, n, kk);
        if (pf) stageB(t + 1, cur ^ 1);
        __builtin_amdgcn_s_barrier();
        quad(0, 1);
        __builtin_amdgcn_s_barrier();

        // ---- phase 2: quadrant (1,1). Reads: af[4..7] (8). Reuse bf nq1.
#pragma unroll
        for (int m = 0; m < 4; ++m)
#pragma unroll
            for (int kk = 0; kk < 2; ++kk) af[m][kk] = lda(1, m, kk);
        __builtin_amdgcn_s_barrier();
        quad(1, 1);
        __builtin_amdgcn_s_barrier();

        // ---- phase 3: quadrant (1,0). Reads: bf nq0 (4). Reuse af[4..7].
#pragma unroll
        for (int n = 0; n < 2; ++n)
#pragma unroll
            for (int kk = 0; kk < 2; ++kk) bf[n][kk] = ldb(0, n, kk);
        __builtin_amdgcn_s_barrier();
        quad(1, 0);
        if (pf) {
            asm volatile("s_waitcnt vmcnt(0)" ::: "memory");
            __builtin_amdgcn_s_barrier();
        }
    }

    // ---- epilogue: C/D col = lane&15, row = lq*4 + q ----
    int crow = row0 + wr * 128;
    int ccol = col0 + wc * 64;
#pragma unroll
    for (int nq = 0; nq < 2; ++nq)
#pragma unroll
        for (int n = 0; n < 2; ++n) {
            int col = ccol + nq * 32 + n * 16 + l16;
            float b = bias[col];
#pragma unroll
            for (int mq = 0; mq < 2; ++mq)
#pragma unroll
                for (int m = 0; m < 4; ++m) {
                    int r = crow + mq * 64 + m * 16 + lq * 4;
#pragma unroll
                    for (int q = 0; q < 4; ++q)
                        out[(size_t)(r + q) * D_MODEL + col] = acc[mq][nq][m][n][q] + b;
                }
        }
}

// fallback (ws too small for Xb): reg-staged f32->bf16, single buffer 128x128
__global__ __launch_bounds__(256)
void gemm_fallback(const float* __restrict__ X, const unsigned short* __restrict__ Wp,
                   const float* __restrict__ bias, float* __restrict__ out, int N) {
    __shared__ __align__(16) unsigned short As[128][64];
    __shared__ __align__(16) unsigned short Bs[128][64];

    int flat = blockIdx.x;
    int swz  = ((gridDim.x & 7) == 0)
             ? (flat & 7) * (gridDim.x >> 3) + (flat >> 3) : flat;
    const int nColBlk = D_MODEL / 128;
    int row0 = (swz / nColBlk) * 128;
    int col0 = (swz % nColBlk) * 128;

    int tid  = threadIdx.x;
    int wave = tid >> 6;
    int lane = tid & 63;
    int wr   = wave >> 1;
    int wc   = wave & 1;
    int l16  = lane & 15;
    int srow  = lane >> 3;
    int skoff = ((lane & 7) ^ srow) << 3;

    f32x4 acc[4][4];
#pragma unroll
    for (int m = 0; m < 4; ++m)
#pragma unroll
        for (int n = 0; n < 4; ++n)
            acc[m][n] = (f32x4){0.f, 0.f, 0.f, 0.f};

    for (int k0 = 0; k0 < D_MODEL; k0 += 64) {
        __syncthreads();
#pragma unroll
        for (int i = 0; i < 4; ++i) {
            int c   = i * 256 + tid;
            int r   = c >> 3;
            int seg = c & 7;
            const float* gp = X + (size_t)(row0 + r) * D_MODEL + k0 + seg * 8;
            f32x4 x0 = *reinterpret_cast<const f32x4*>(gp);
            f32x4 x1 = *reinterpret_cast<const f32x4*>(gp + 4);
            u16x8 v;
#pragma unroll
            for (int e = 0; e < 4; ++e) { v[e] = f2bf(x0[e]); v[e + 4] = f2bf(x1[e]); }
            int off = (seg * 16) ^ ((r & 7) << 4);
            *reinterpret_cast<u16x8*>((char*)&As[0][0] + r * 128 + off) = v;
        }
#pragma unroll
        for (int i = 0; i < 4; ++i) {
            int r0 = (wave * 4 + i) * 8;
            const unsigned short* g = Wp + (size_t)(col0 + r0 + srow) * D_MODEL + k0 + skoff;
            __builtin_amdgcn_global_load_lds(
                (const __attribute__((address_space(1))) void*)g,
                (__attribute__((address_space(3))) void*)&Bs[r0][0], 16, 0, 0);
        }
        __syncthreads();
#pragma unroll
        for (int kk = 0; kk < 2; ++kk) {
            bf16x8 af[4], bf_[4];
#pragma unroll
            for (int m = 0; m < 4; ++m) {
                int row = wr * 64 + m * 16 + l16;
                int o   = ((lane >> 4) * 16 + kk * 64) ^ ((row & 7) << 4);
                af[m] = *reinterpret_cast<const bf16x8*>((const char*)&As[0][0] + row * 128 + o);
            }
#pragma unroll
            for (int n = 0; n < 4; ++n) {
                int row = wc * 64 + n * 16 + l16;
                int o   = ((lane >> 4) * 16 + kk * 64) ^ ((row & 7) << 4);
                bf_[n] = *reinterpret_cast<const bf16x8*>((const char*)&Bs[0][0] + row * 128 + o);
            }
#pragma unroll
            for (int m = 0; m < 4; ++m)
#pragma unroll
                for (int n = 0; n < 4; ++n)
                    acc[m][n] = __builtin_amdgcn_mfma_f32_16x16x32_bf16(
                        af[m], bf_[n], acc[m][n], 0, 0, 0);
        }
    }

    int crow = row0 + wr * 64;
    int ccol = col0 + wc * 64;
#pragma unroll
    for (int n = 0; n < 4; ++n) {
        int col = ccol + n * 16 + l16;
        float b = bias[col];
#pragma unroll
        for (int m = 0; m < 4; ++m) {
            int r = crow + m * 16 + (lane >> 4) * 4;
#pragma unroll
            for (int q = 0; q < 4; ++q)
                out[(size_t)(r + q) * D_MODEL + col] = acc[m][n][q] + b;
        }
    }
}

// ---------- launch ----------

extern "C" void kernel_launch(void* const* d_in, const int* in_sizes, int n_in,
                              void* d_out, int out_size, void* d_ws, size_t ws_size,
                              hipStream_t stream) {
    const float* x    = (const float*)d_in[0];
    const float* w    = (const float*)d_in[1];
    const float* bias = (const float*)d_in[2];
    float* out        = (float*)d_out;
    const int N       = in_sizes[0] / D_MODEL;   // 32768

    char* ws               = (char*)d_ws;
    unsigned*       ma_u   = (unsigned*)(ws);
    unsigned*       mw_u   = (unsigned*)(ws + 4096);
    float*          s      = (float*)(ws + 8192);
    unsigned short* Wp     = (unsigned short*)(ws + 16384);
    unsigned short* Xb     = (unsigned short*)(ws + 16384 + (size_t)D_MODEL * D_MODEL * 2);
    const int nPart        = N / CC_ROWS;   // 2048
    float*          part   = (float*)(ws + 16384 + (size_t)D_MODEL * D_MODEL * 2
                                               + (size_t)N * D_MODEL * 2);

    size_t need = 16384 + (size_t)D_MODEL * D_MODEL * 2 + (size_t)N * D_MODEL * 2
                + (size_t)nPart * D_MODEL * 4;
    bool preconv = ws_size >= need;

    init_u32<<<8, 256, 0, stream>>>((unsigned*)ws, 2048);

    if (preconv) {
        colmax_convert<<<nPart, 256, 0, stream>>>(x, part, Xb);
        reduce_partial<<<dim3(D_MODEL / 256, nPart / 64), 256, 0, stream>>>(part, ma_u);
    } else {
        colmax_kernel<<<dim3(D_MODEL / 256, 64), 256, 0, stream>>>(x, N / 64, D_MODEL, ma_u);
    }
    colmax_kernel<<<dim3(D_MODEL / 256, 16), 256, 0, stream>>>(w, D_MODEL / 16, D_MODEL, mw_u);
    scale_kernel<<<D_MODEL / 256, 256, 0, stream>>>(ma_u, mw_u, s);
    build_w_kernel<<<D_MODEL, 256, 0, stream>>>(w, s, Wp);

    if (preconv) {
        int nblk = (N / GBM) * (D_MODEL / GBN);   // 512
        gemm_8ph<<<nblk, 512, 0, stream>>>(Xb, Wp, bias, out);
    } else {
        int nblk = (N / 128) * (D_MODEL / 128);
        gemm_fallback<<<nblk, 256, 0, stream>>>(x, Wp, bias, out, N);
    }
}

// Round 7
// 167.984 us; speedup vs baseline: 1.0169x; 1.0169x over previous
//
#include <hip/hip_runtime.h>
#include <hip/hip_bf16.h>
#include <stdint.h>

#define D_MODEL 1024

typedef __attribute__((ext_vector_type(4))) float  f32x4;
typedef __attribute__((ext_vector_type(8))) __bf16 bf16x8;
typedef __attribute__((ext_vector_type(8))) unsigned short u16x8;
typedef __attribute__((ext_vector_type(4))) unsigned short u16x4;

// ---------- helpers ----------

__device__ __forceinline__ unsigned order_map(float x) {
    unsigned u = __float_as_uint(x);
    return (u & 0x80000000u) ? ~u : (u | 0x80000000u);
}
__device__ __forceinline__ float order_unmap(unsigned m) {
    unsigned b = (m & 0x80000000u) ? (m & 0x7fffffffu) : ~m;
    return __uint_as_float(b);
}
__device__ __forceinline__ unsigned short f2bf(float f) {
    unsigned u = __float_as_uint(f);
    u += 0x7fffu + ((u >> 16) & 1u);
    return (unsigned short)(u >> 16);
}

// ---------- prelude kernels (unchanged — at BW floor) ----------

__global__ void init_u32(unsigned* __restrict__ p, int n) {
    int i = blockIdx.x * blockDim.x + threadIdx.x;
    if (i < n) p[i] = 0u;
}

__global__ void colmax_kernel(const float* __restrict__ src, int rows_per_slab,
                              int cols, unsigned* __restrict__ out_u) {
    int k = blockIdx.x * blockDim.x + threadIdx.x;
    const float* p = src + (size_t)blockIdx.y * rows_per_slab * cols + k;
    float m = -__builtin_inff();
#pragma unroll 4
    for (int r = 0; r < rows_per_slab; ++r)
        m = fmaxf(m, p[(size_t)r * cols]);
    atomicMax(&out_u[k], order_map(m));
}

#define CC_ROWS 16
__global__ __launch_bounds__(256)
void colmax_convert(const float* __restrict__ x,
                    float* __restrict__ partial,
                    unsigned short* __restrict__ xb) {
    int c4 = threadIdx.x * 4;
    size_t base = (size_t)blockIdx.x * CC_ROWS * D_MODEL + c4;
    f32x4 m4 = {-__builtin_inff(), -__builtin_inff(), -__builtin_inff(), -__builtin_inff()};
#pragma unroll 8
    for (int r = 0; r < CC_ROWS; ++r) {
        f32x4 v = *reinterpret_cast<const f32x4*>(&x[base + (size_t)r * D_MODEL]);
        u16x4 o;
#pragma unroll
        for (int e = 0; e < 4; ++e) { m4[e] = fmaxf(m4[e], v[e]); o[e] = f2bf(v[e]); }
        *reinterpret_cast<u16x4*>(&xb[base + (size_t)r * D_MODEL]) = o;
    }
    *reinterpret_cast<f32x4*>(&partial[(size_t)blockIdx.x * D_MODEL + c4]) = m4;
}

__global__ void reduce_partial(const float* __restrict__ partial,
                               unsigned* __restrict__ ma_u) {
    int col  = blockIdx.x * 256 + threadIdx.x;
    int b0   = blockIdx.y * 64;
    float m = -__builtin_inff();
#pragma unroll 8
    for (int i = 0; i < 64; ++i)
        m = fmaxf(m, partial[(size_t)(b0 + i) * D_MODEL + col]);
    atomicMax(&ma_u[col], order_map(m));
}

__global__ void scale_kernel(const unsigned* __restrict__ ma_u,
                             const unsigned* __restrict__ mw_u,
                             float* __restrict__ s) {
    int k = blockIdx.x * blockDim.x + threadIdx.x;
    if (k < D_MODEL) {
        float ma = order_unmap(ma_u[k]);
        float mw = order_unmap(mw_u[k]);
        s[k] = sqrtf(ma) / sqrtf(mw);   // ALPHA = 0.5
    }
}

__global__ void build_w_kernel(const float* __restrict__ W, const float* __restrict__ s,
                               unsigned short* __restrict__ Wp) {
    int j  = blockIdx.x;
    int k4 = threadIdx.x * 4;
    float sj = s[j];
    f32x4 w  = *reinterpret_cast<const f32x4*>(&W[(size_t)j * D_MODEL + k4]);
    f32x4 sk = *reinterpret_cast<const f32x4*>(&s[k4]);
    u16x4 o;
#pragma unroll
    for (int i = 0; i < 4; ++i) o[i] = f2bf(sj * w[i] / sk[i]);
    *reinterpret_cast<u16x4*>(&Wp[(size_t)j * D_MODEL + k4]) = o;
}

// ---------- GEMM: 256x256 tile, 8 waves (2Mx4N), BK=64 ----------
// De-lockstepped K-loop: ONE vmcnt(0)+barrier per K-tile (buffer swap only).
// Within a tile: stage(t+1)->buf^1 issued first, then 24 ds_read_b128 + 64 MFMA
// in 2 clusters; compiler's fine lgkmcnt + 2 waves/SIMD overlap LDS with MFMA.
// Block map: XCD xcd=flat&7 -> col panel (xcd&3), row chunk ((xcd>>2)*64 + flat>>3):
// XCDs 0..3 stream the SAME Xb rows concurrently (L3-resident window).
#define GBM 256
#define GBN 256
#define GBK 64
#define GNT (D_MODEL / GBK)   // 16

__global__ __launch_bounds__(512, 2)
void gemm_main(const unsigned short* __restrict__ Xb,
               const unsigned short* __restrict__ Wp,
               const float* __restrict__ bias,
               float* __restrict__ out) {
    __shared__ __align__(16) unsigned short As[2][GBM][GBK];   // 64 KB
    __shared__ __align__(16) unsigned short Bs[2][GBN][GBK];   // 64 KB

    int flat = blockIdx.x;
    int xcd  = flat & 7;
    int idx  = flat >> 3;                    // 0..63 within XCD
    int col0 = (xcd & 3) * GBN;              // 4 col panels
    int row0 = ((xcd >> 2) * 64 + idx) * GBM;

    int tid  = threadIdx.x;
    int wave = tid >> 6;
    int lane = tid & 63;
    int wr   = wave >> 2;      // 0..1 : rows wr*128
    int wc   = wave & 3;       // 0..3 : cols wc*64
    int l16  = lane & 15;
    int lq   = lane >> 4;      // 0..3 : k-quarter
    int srow  = lane >> 3;                   // staging row within 8-row group
    int skoff = ((lane & 7) ^ srow) << 3;    // pre-swizzled source k-offset (elems)

    f32x4 acc[2][2][4][2];
#pragma unroll
    for (int mq = 0; mq < 2; ++mq)
#pragma unroll
        for (int nq = 0; nq < 2; ++nq)
#pragma unroll
            for (int m = 0; m < 4; ++m)
#pragma unroll
                for (int n = 0; n < 2; ++n)
                    acc[mq][nq][m][n] = (f32x4){0.f, 0.f, 0.f, 0.f};

    auto stageA = [&](int t, int b) {
        int k0 = t * GBK;
#pragma unroll
        for (int i = 0; i < 4; ++i) {
            int rg = wave * 4 + i;
            const unsigned short* g = Xb + (size_t)(row0 + rg * 8 + srow) * D_MODEL + k0 + skoff;
            __builtin_amdgcn_global_load_lds(
                (const __attribute__((address_space(1))) void*)g,
                (__attribute__((address_space(3))) void*)&As[b][rg * 8][0], 16, 0, 0);
        }
    };
    auto stageB = [&](int t, int b) {
        int k0 = t * GBK;
#pragma unroll
        for (int i = 0; i < 4; ++i) {
            int rg = wave * 4 + i;
            const unsigned short* g = Wp + (size_t)(col0 + rg * 8 + srow) * D_MODEL + k0 + skoff;
            __builtin_amdgcn_global_load_lds(
                (const __attribute__((address_space(1))) void*)g,
                (__attribute__((address_space(3))) void*)&Bs[b][rg * 8][0], 16, 0, 0);
        }
    };

    // prologue: tile 0
    stageA(0, 0); stageB(0, 0);
    asm volatile("s_waitcnt vmcnt(0)" ::: "memory");
    __builtin_amdgcn_s_barrier();

#pragma unroll 1
    for (int t = 0; t < GNT; ++t) {
        int cur = t & 1;
        bool pf = (t + 1 < GNT);
        const char* Ab = (const char*)&As[cur][0][0];
        const char* Bb = (const char*)&Bs[cur][0][0];

        // issue next-tile staging FIRST; it lands during this tile's compute.
        // buf[cur^1] was last READ during tile t-1; the end-of-(t-1) barrier
        // guarantees all waves are done with it.
        if (pf) { stageA(t + 1, cur ^ 1); stageB(t + 1, cur ^ 1); }

        auto lda = [&](int mq, int m, int kk) {
            int row  = wr * 128 + mq * 64 + m * 16 + l16;
            int slot = (kk * 4 + lq) ^ (row & 7);
            return *reinterpret_cast<const bf16x8*>(Ab + row * 128 + slot * 16);
        };
        auto ldb = [&](int nq, int n, int kk) {
            int row  = wc * 64 + nq * 32 + n * 16 + l16;
            int slot = (kk * 4 + lq) ^ (row & 7);
            return *reinterpret_cast<const bf16x8*>(Bb + row * 128 + slot * 16);
        };

        // all 8 B-frags once (deduped)
        bf16x8 bf[2][2][2];
#pragma unroll
        for (int nq = 0; nq < 2; ++nq)
#pragma unroll
            for (int n = 0; n < 2; ++n)
#pragma unroll
                for (int kk = 0; kk < 2; ++kk)
                    bf[nq][n][kk] = ldb(nq, n, kk);

        // cluster mq=0
        {
            bf16x8 af[4][2];
#pragma unroll
            for (int m = 0; m < 4; ++m)
#pragma unroll
                for (int kk = 0; kk < 2; ++kk) af[m][kk] = lda(0, m, kk);
            __builtin_amdgcn_s_setprio(1);
#pragma unroll
            for (int m = 0; m < 4; ++m)
#pragma unroll
                for (int nq = 0; nq < 2; ++nq)
#pragma unroll
                    for (int n = 0; n < 2; ++n)
#pragma unroll
                        for (int kk = 0; kk < 2; ++kk)
                            acc[0][nq][m][n] = __builtin_amdgcn_mfma_f32_16x16x32_bf16(
                                af[m][kk], bf[nq][n][kk], acc[0][nq][m][n], 0, 0, 0);
            __builtin_amdgcn_s_setprio(0);
        }
        // cluster mq=1
        {
            bf16x8 af[4][2];
#pragma unroll
            for (int m = 0; m < 4; ++m)
#pragma unroll
                for (int kk = 0; kk < 2; ++kk) af[m][kk] = lda(1, m, kk);
            __builtin_amdgcn_s_setprio(1);
#pragma unroll
            for (int m = 0; m < 4; ++m)
#pragma unroll
                for (int nq = 0; nq < 2; ++nq)
#pragma unroll
                    for (int n = 0; n < 2; ++n)
#pragma unroll
                        for (int kk = 0; kk < 2; ++kk)
                            acc[1][nq][m][n] = __builtin_amdgcn_mfma_f32_16x16x32_bf16(
                                af[m][kk], bf[nq][n][kk], acc[1][nq][m][n], 0, 0, 0);
            __builtin_amdgcn_s_setprio(0);
        }

        if (pf) {
            asm volatile("s_waitcnt vmcnt(0)" ::: "memory");
            __builtin_amdgcn_s_barrier();
        }
    }

    // ---- epilogue: C/D col = lane&15, row = lq*4 + q ----
    int crow = row0 + wr * 128;
    int ccol = col0 + wc * 64;
#pragma unroll
    for (int nq = 0; nq < 2; ++nq)
#pragma unroll
        for (int n = 0; n < 2; ++n) {
            int col = ccol + nq * 32 + n * 16 + l16;
            float b = bias[col];
#pragma unroll
            for (int mq = 0; mq < 2; ++mq)
#pragma unroll
                for (int m = 0; m < 4; ++m) {
                    int r = crow + mq * 64 + m * 16 + lq * 4;
#pragma unroll
                    for (int q = 0; q < 4; ++q)
                        out[(size_t)(r + q) * D_MODEL + col] = acc[mq][nq][m][n][q] + b;
                }
        }
}

// fallback (ws too small for Xb): reg-staged f32->bf16, single buffer 128x128
__global__ __launch_bounds__(256)
void gemm_fallback(const float* __restrict__ X, const unsigned short* __restrict__ Wp,
                   const float* __restrict__ bias, float* __restrict__ out, int N) {
    __shared__ __align__(16) unsigned short As[128][64];
    __shared__ __align__(16) unsigned short Bs[128][64];

    int flat = blockIdx.x;
    int swz  = ((gridDim.x & 7) == 0)
             ? (flat & 7) * (gridDim.x >> 3) + (flat >> 3) : flat;
    const int nColBlk = D_MODEL / 128;
    int row0 = (swz / nColBlk) * 128;
    int col0 = (swz % nColBlk) * 128;

    int tid  = threadIdx.x;
    int wave = tid >> 6;
    int lane = tid & 63;
    int wr   = wave >> 1;
    int wc   = wave & 1;
    int l16  = lane & 15;
    int srow  = lane >> 3;
    int skoff = ((lane & 7) ^ srow) << 3;

    f32x4 acc[4][4];
#pragma unroll
    for (int m = 0; m < 4; ++m)
#pragma unroll
        for (int n = 0; n < 4; ++n)
            acc[m][n] = (f32x4){0.f, 0.f, 0.f, 0.f};

    for (int k0 = 0; k0 < D_MODEL; k0 += 64) {
        __syncthreads();
#pragma unroll
        for (int i = 0; i < 4; ++i) {
            int c   = i * 256 + tid;
            int r   = c >> 3;
            int seg = c & 7;
            const float* gp = X + (size_t)(row0 + r) * D_MODEL + k0 + seg * 8;
            f32x4 x0 = *reinterpret_cast<const f32x4*>(gp);
            f32x4 x1 = *reinterpret_cast<const f32x4*>(gp + 4);
            u16x8 v;
#pragma unroll
            for (int e = 0; e < 4; ++e) { v[e] = f2bf(x0[e]); v[e + 4] = f2bf(x1[e]); }
            int off = (seg * 16) ^ ((r & 7) << 4);
            *reinterpret_cast<u16x8*>((char*)&As[0][0] + r * 128 + off) = v;
        }
#pragma unroll
        for (int i = 0; i < 4; ++i) {
            int r0 = (wave * 4 + i) * 8;
            const unsigned short* g = Wp + (size_t)(col0 + r0 + srow) * D_MODEL + k0 + skoff;
            __builtin_amdgcn_global_load_lds(
                (const __attribute__((address_space(1))) void*)g,
                (__attribute__((address_space(3))) void*)&Bs[r0][0], 16, 0, 0);
        }
        __syncthreads();
#pragma unroll
        for (int kk = 0; kk < 2; ++kk) {
            bf16x8 af[4], bf_[4];
#pragma unroll
            for (int m = 0; m < 4; ++m) {
                int row = wr * 64 + m * 16 + l16;
                int o   = ((lane >> 4) * 16 + kk * 64) ^ ((row & 7) << 4);
                af[m] = *reinterpret_cast<const bf16x8*>((const char*)&As[0][0] + row * 128 + o);
            }
#pragma unroll
            for (int n = 0; n < 4; ++n) {
                int row = wc * 64 + n * 16 + l16;
                int o   = ((lane >> 4) * 16 + kk * 64) ^ ((row & 7) << 4);
                bf_[n] = *reinterpret_cast<const bf16x8*>((const char*)&Bs[0][0] + row * 128 + o);
            }
#pragma unroll
            for (int m = 0; m < 4; ++m)
#pragma unroll
                for (int n = 0; n < 4; ++n)
                    acc[m][n] = __builtin_amdgcn_mfma_f32_16x16x32_bf16(
                        af[m], bf_[n], acc[m][n], 0, 0, 0);
        }
    }

    int crow = row0 + wr * 64;
    int ccol = col0 + wc * 64;
#pragma unroll
    for (int n = 0; n < 4; ++n) {
        int col = ccol + n * 16 + l16;
        float b = bias[col];
#pragma unroll
        for (int m = 0; m < 4; ++m) {
            int r = crow + m * 16 + (lane >> 4) * 4;
#pragma unroll
            for (int q = 0; q < 4; ++q)
                out[(size_t)(r + q) * D_MODEL + col] = acc[m][n][q] + b;
        }
    }
}

// ---------- launch ----------

extern "C" void kernel_launch(void* const* d_in, const int* in_sizes, int n_in,
                              void* d_out, int out_size, void* d_ws, size_t ws_size,
                              hipStream_t stream) {
    const float* x    = (const float*)d_in[0];
    const float* w    = (const float*)d_in[1];
    const float* bias = (const float*)d_in[2];
    float* out        = (float*)d_out;
    const int N       = in_sizes[0] / D_MODEL;   // 32768

    char* ws               = (char*)d_ws;
    unsigned*       ma_u   = (unsigned*)(ws);
    unsigned*       mw_u   = (unsigned*)(ws + 4096);
    float*          s      = (float*)(ws + 8192);
    unsigned short* Wp     = (unsigned short*)(ws + 16384);
    unsigned short* Xb     = (unsigned short*)(ws + 16384 + (size_t)D_MODEL * D_MODEL * 2);
    const int nPart        = N / CC_ROWS;   // 2048
    float*          part   = (float*)(ws + 16384 + (size_t)D_MODEL * D_MODEL * 2
                                               + (size_t)N * D_MODEL * 2);

    size_t need = 16384 + (size_t)D_MODEL * D_MODEL * 2 + (size_t)N * D_MODEL * 2
                + (size_t)nPart * D_MODEL * 4;
    bool preconv = ws_size >= need;

    init_u32<<<8, 256, 0, stream>>>((unsigned*)ws, 2048);

    if (preconv) {
        colmax_convert<<<nPart, 256, 0, stream>>>(x, part, Xb);
        reduce_partial<<<dim3(D_MODEL / 256, nPart / 64), 256, 0, stream>>>(part, ma_u);
    } else {
        colmax_kernel<<<dim3(D_MODEL / 256, 64), 256, 0, stream>>>(x, N / 64, D_MODEL, ma_u);
    }
    colmax_kernel<<<dim3(D_MODEL / 256, 16), 256, 0, stream>>>(w, D_MODEL / 16, D_MODEL, mw_u);
    scale_kernel<<<D_MODEL / 256, 256, 0, stream>>>(ma_u, mw_u, s);
    build_w_kernel<<<D_MODEL, 256, 0, stream>>>(w, s, Wp);

    if (preconv) {
        int nblk = (N / GBM) * (D_MODEL / GBN);   // 512
        gemm_main<<<nblk, 512, 0, stream>>>(Xb, Wp, bias, out);
    } else {
        int nblk = (N / 128) * (D_MODEL / 128);
        gemm_fallback<<<nblk, 256, 0, stream>>>(x, Wp, bias, out, N);
    }
}

// Round 8
// 160.488 us; speedup vs baseline: 1.0644x; 1.0467x over previous
//
#include <hip/hip_runtime.h>
#include <hip/hip_bf16.h>
#include <stdint.h>

#define D_MODEL 1024

typedef __attribute__((ext_vector_type(4))) float  f32x4;
typedef __attribute__((ext_vector_type(8))) __bf16 bf16x8;
typedef __attribute__((ext_vector_type(8))) unsigned short u16x8;
typedef __attribute__((ext_vector_type(4))) unsigned short u16x4;

// ---------- helpers ----------

__device__ __forceinline__ unsigned order_map(float x) {
    unsigned u = __float_as_uint(x);
    return (u & 0x80000000u) ? ~u : (u | 0x80000000u);
}
__device__ __forceinline__ float order_unmap(unsigned m) {
    unsigned b = (m & 0x80000000u) ? (m & 0x7fffffffu) : ~m;
    return __uint_as_float(b);
}
__device__ __forceinline__ unsigned short f2bf(float f) {
    unsigned u = __float_as_uint(f);
    u += 0x7fffu + ((u >> 16) & 1u);
    return (unsigned short)(u >> 16);
}

// ---------- prelude kernels (unchanged — at BW floor) ----------

__global__ void init_u32(unsigned* __restrict__ p, int n) {
    int i = blockIdx.x * blockDim.x + threadIdx.x;
    if (i < n) p[i] = 0u;
}

__global__ void colmax_kernel(const float* __restrict__ src, int rows_per_slab,
                              int cols, unsigned* __restrict__ out_u) {
    int k = blockIdx.x * blockDim.x + threadIdx.x;
    const float* p = src + (size_t)blockIdx.y * rows_per_slab * cols + k;
    float m = -__builtin_inff();
#pragma unroll 4
    for (int r = 0; r < rows_per_slab; ++r)
        m = fmaxf(m, p[(size_t)r * cols]);
    atomicMax(&out_u[k], order_map(m));
}

#define CC_ROWS 16
__global__ __launch_bounds__(256)
void colmax_convert(const float* __restrict__ x,
                    float* __restrict__ partial,
                    unsigned short* __restrict__ xb) {
    int c4 = threadIdx.x * 4;
    size_t base = (size_t)blockIdx.x * CC_ROWS * D_MODEL + c4;
    f32x4 m4 = {-__builtin_inff(), -__builtin_inff(), -__builtin_inff(), -__builtin_inff()};
#pragma unroll 8
    for (int r = 0; r < CC_ROWS; ++r) {
        f32x4 v = *reinterpret_cast<const f32x4*>(&x[base + (size_t)r * D_MODEL]);
        u16x4 o;
#pragma unroll
        for (int e = 0; e < 4; ++e) { m4[e] = fmaxf(m4[e], v[e]); o[e] = f2bf(v[e]); }
        *reinterpret_cast<u16x4*>(&xb[base + (size_t)r * D_MODEL]) = o;
    }
    *reinterpret_cast<f32x4*>(&partial[(size_t)blockIdx.x * D_MODEL + c4]) = m4;
}

__global__ void reduce_partial(const float* __restrict__ partial,
                               unsigned* __restrict__ ma_u) {
    int col  = blockIdx.x * 256 + threadIdx.x;
    int b0   = blockIdx.y * 64;
    float m = -__builtin_inff();
#pragma unroll 8
    for (int i = 0; i < 64; ++i)
        m = fmaxf(m, partial[(size_t)(b0 + i) * D_MODEL + col]);
    atomicMax(&ma_u[col], order_map(m));
}

__global__ void scale_kernel(const unsigned* __restrict__ ma_u,
                             const unsigned* __restrict__ mw_u,
                             float* __restrict__ s) {
    int k = blockIdx.x * blockDim.x + threadIdx.x;
    if (k < D_MODEL) {
        float ma = order_unmap(ma_u[k]);
        float mw = order_unmap(mw_u[k]);
        s[k] = sqrtf(ma) / sqrtf(mw);   // ALPHA = 0.5
    }
}

__global__ void build_w_kernel(const float* __restrict__ W, const float* __restrict__ s,
                               unsigned short* __restrict__ Wp) {
    int j  = blockIdx.x;
    int k4 = threadIdx.x * 4;
    float sj = s[j];
    f32x4 w  = *reinterpret_cast<const f32x4*>(&W[(size_t)j * D_MODEL + k4]);
    f32x4 sk = *reinterpret_cast<const f32x4*>(&s[k4]);
    u16x4 o;
#pragma unroll
    for (int i = 0; i < 4; ++i) o[i] = f2bf(sj * w[i] / sk[i]);
    *reinterpret_cast<u16x4*>(&Wp[(size_t)j * D_MODEL + k4]) = o;
}

// ---------- GEMM: 256x256 tile, 8 waves (2Mx4N), BK=64 ----------
// R8 change: WITHIN-XCD Xb reuse. xcd=flat&7, j=flat>>3; panel=j&3,
// chunk=(xcd<<4)+(j>>2). Each XCD's 32 resident blocks = 8 chunks x 4 panels:
// every Xb chunk is read by 4 blocks ON THE SAME XCD (1 L2 fill + 3 L2 hits),
// and each chunk is fetched by exactly one XCD -> Xb HBM = 64 MB once.
// Fabric per tile-step 16 MB -> ~3 MB; staging stops being the binding term.
#define GBM 256
#define GBN 256
#define GBK 64
#define GNT (D_MODEL / GBK)   // 16

__global__ __launch_bounds__(512, 2)
void gemm_main(const unsigned short* __restrict__ Xb,
               const unsigned short* __restrict__ Wp,
               const float* __restrict__ bias,
               float* __restrict__ out) {
    __shared__ __align__(16) unsigned short As[2][GBM][GBK];   // 64 KB
    __shared__ __align__(16) unsigned short Bs[2][GBN][GBK];   // 64 KB

    int flat  = blockIdx.x;
    int xcd   = flat & 7;
    int j     = flat >> 3;                    // 0..63
    int col0  = (j & 3) * GBN;                // 4 col panels
    int row0  = ((xcd << 4) + (j >> 2)) * GBM;  // chunk 0..127

    int tid  = threadIdx.x;
    int wave = tid >> 6;
    int lane = tid & 63;
    int wr   = wave >> 2;      // 0..1 : rows wr*128
    int wc   = wave & 3;       // 0..3 : cols wc*64
    int l16  = lane & 15;
    int lq   = lane >> 4;      // 0..3 : k-quarter
    int srow  = lane >> 3;                   // staging row within 8-row group
    int skoff = ((lane & 7) ^ srow) << 3;    // pre-swizzled source k-offset (elems)

    f32x4 acc[2][2][4][2];
#pragma unroll
    for (int mq = 0; mq < 2; ++mq)
#pragma unroll
        for (int nq = 0; nq < 2; ++nq)
#pragma unroll
            for (int m = 0; m < 4; ++m)
#pragma unroll
                for (int n = 0; n < 2; ++n)
                    acc[mq][nq][m][n] = (f32x4){0.f, 0.f, 0.f, 0.f};

    auto stageA = [&](int t, int b) {
        int k0 = t * GBK;
#pragma unroll
        for (int i = 0; i < 4; ++i) {
            int rg = wave * 4 + i;
            const unsigned short* g = Xb + (size_t)(row0 + rg * 8 + srow) * D_MODEL + k0 + skoff;
            __builtin_amdgcn_global_load_lds(
                (const __attribute__((address_space(1))) void*)g,
                (__attribute__((address_space(3))) void*)&As[b][rg * 8][0], 16, 0, 0);
        }
    };
    auto stageB = [&](int t, int b) {
        int k0 = t * GBK;
#pragma unroll
        for (int i = 0; i < 4; ++i) {
            int rg = wave * 4 + i;
            const unsigned short* g = Wp + (size_t)(col0 + rg * 8 + srow) * D_MODEL + k0 + skoff;
            __builtin_amdgcn_global_load_lds(
                (const __attribute__((address_space(1))) void*)g,
                (__attribute__((address_space(3))) void*)&Bs[b][rg * 8][0], 16, 0, 0);
        }
    };

    // prologue: tile 0
    stageA(0, 0); stageB(0, 0);
    asm volatile("s_waitcnt vmcnt(0)" ::: "memory");
    __builtin_amdgcn_s_barrier();

#pragma unroll 1
    for (int t = 0; t < GNT; ++t) {
        int cur = t & 1;
        bool pf = (t + 1 < GNT);
        const char* Ab = (const char*)&As[cur][0][0];
        const char* Bb = (const char*)&Bs[cur][0][0];

        // issue next-tile staging FIRST; it lands during this tile's compute.
        if (pf) { stageA(t + 1, cur ^ 1); stageB(t + 1, cur ^ 1); }

        auto lda = [&](int mq, int m, int kk) {
            int row  = wr * 128 + mq * 64 + m * 16 + l16;
            int slot = (kk * 4 + lq) ^ (row & 7);
            return *reinterpret_cast<const bf16x8*>(Ab + row * 128 + slot * 16);
        };
        auto ldb = [&](int nq, int n, int kk) {
            int row  = wc * 64 + nq * 32 + n * 16 + l16;
            int slot = (kk * 4 + lq) ^ (row & 7);
            return *reinterpret_cast<const bf16x8*>(Bb + row * 128 + slot * 16);
        };

        // all 8 B-frags once (deduped)
        bf16x8 bf[2][2][2];
#pragma unroll
        for (int nq = 0; nq < 2; ++nq)
#pragma unroll
            for (int n = 0; n < 2; ++n)
#pragma unroll
                for (int kk = 0; kk < 2; ++kk)
                    bf[nq][n][kk] = ldb(nq, n, kk);

        // cluster mq=0
        {
            bf16x8 af[4][2];
#pragma unroll
            for (int m = 0; m < 4; ++m)
#pragma unroll
                for (int kk = 0; kk < 2; ++kk) af[m][kk] = lda(0, m, kk);
            __builtin_amdgcn_s_setprio(1);
#pragma unroll
            for (int m = 0; m < 4; ++m)
#pragma unroll
                for (int nq = 0; nq < 2; ++nq)
#pragma unroll
                    for (int n = 0; n < 2; ++n)
#pragma unroll
                        for (int kk = 0; kk < 2; ++kk)
                            acc[0][nq][m][n] = __builtin_amdgcn_mfma_f32_16x16x32_bf16(
                                af[m][kk], bf[nq][n][kk], acc[0][nq][m][n], 0, 0, 0);
            __builtin_amdgcn_s_setprio(0);
        }
        // cluster mq=1
        {
            bf16x8 af[4][2];
#pragma unroll
            for (int m = 0; m < 4; ++m)
#pragma unroll
                for (int kk = 0; kk < 2; ++kk) af[m][kk] = lda(1, m, kk);
            __builtin_amdgcn_s_setprio(1);
#pragma unroll
            for (int m = 0; m < 4; ++m)
#pragma unroll
                for (int nq = 0; nq < 2; ++nq)
#pragma unroll
                    for (int n = 0; n < 2; ++n)
#pragma unroll
                        for (int kk = 0; kk < 2; ++kk)
                            acc[1][nq][m][n] = __builtin_amdgcn_mfma_f32_16x16x32_bf16(
                                af[m][kk], bf[nq][n][kk], acc[1][nq][m][n], 0, 0, 0);
            __builtin_amdgcn_s_setprio(0);
        }

        if (pf) {
            asm volatile("s_waitcnt vmcnt(0)" ::: "memory");
            __builtin_amdgcn_s_barrier();
        }
    }

    // ---- epilogue: C/D col = lane&15, row = lq*4 + q ----
    int crow = row0 + wr * 128;
    int ccol = col0 + wc * 64;
#pragma unroll
    for (int nq = 0; nq < 2; ++nq)
#pragma unroll
        for (int n = 0; n < 2; ++n) {
            int col = ccol + nq * 32 + n * 16 + l16;
            float b = bias[col];
#pragma unroll
            for (int mq = 0; mq < 2; ++mq)
#pragma unroll
                for (int m = 0; m < 4; ++m) {
                    int r = crow + mq * 64 + m * 16 + lq * 4;
#pragma unroll
                    for (int q = 0; q < 4; ++q)
                        out[(size_t)(r + q) * D_MODEL + col] = acc[mq][nq][m][n][q] + b;
                }
        }
}

// fallback (ws too small for Xb): reg-staged f32->bf16, single buffer 128x128
__global__ __launch_bounds__(256)
void gemm_fallback(const float* __restrict__ X, const unsigned short* __restrict__ Wp,
                   const float* __restrict__ bias, float* __restrict__ out, int N) {
    __shared__ __align__(16) unsigned short As[128][64];
    __shared__ __align__(16) unsigned short Bs[128][64];

    int flat = blockIdx.x;
    int swz  = ((gridDim.x & 7) == 0)
             ? (flat & 7) * (gridDim.x >> 3) + (flat >> 3) : flat;
    const int nColBlk = D_MODEL / 128;
    int row0 = (swz / nColBlk) * 128;
    int col0 = (swz % nColBlk) * 128;

    int tid  = threadIdx.x;
    int wave = tid >> 6;
    int lane = tid & 63;
    int wr   = wave >> 1;
    int wc   = wave & 1;
    int l16  = lane & 15;
    int srow  = lane >> 3;
    int skoff = ((lane & 7) ^ srow) << 3;

    f32x4 acc[4][4];
#pragma unroll
    for (int m = 0; m < 4; ++m)
#pragma unroll
        for (int n = 0; n < 4; ++n)
            acc[m][n] = (f32x4){0.f, 0.f, 0.f, 0.f};

    for (int k0 = 0; k0 < D_MODEL; k0 += 64) {
        __syncthreads();
#pragma unroll
        for (int i = 0; i < 4; ++i) {
            int c   = i * 256 + tid;
            int r   = c >> 3;
            int seg = c & 7;
            const float* gp = X + (size_t)(row0 + r) * D_MODEL + k0 + seg * 8;
            f32x4 x0 = *reinterpret_cast<const f32x4*>(gp);
            f32x4 x1 = *reinterpret_cast<const f32x4*>(gp + 4);
            u16x8 v;
#pragma unroll
            for (int e = 0; e < 4; ++e) { v[e] = f2bf(x0[e]); v[e + 4] = f2bf(x1[e]); }
            int off = (seg * 16) ^ ((r & 7) << 4);
            *reinterpret_cast<u16x8*>((char*)&As[0][0] + r * 128 + off) = v;
        }
#pragma unroll
        for (int i = 0; i < 4; ++i) {
            int r0 = (wave * 4 + i) * 8;
            const unsigned short* g = Wp + (size_t)(col0 + r0 + srow) * D_MODEL + k0 + skoff;
            __builtin_amdgcn_global_load_lds(
                (const __attribute__((address_space(1))) void*)g,
                (__attribute__((address_space(3))) void*)&Bs[r0][0], 16, 0, 0);
        }
        __syncthreads();
#pragma unroll
        for (int kk = 0; kk < 2; ++kk) {
            bf16x8 af[4], bf_[4];
#pragma unroll
            for (int m = 0; m < 4; ++m) {
                int row = wr * 64 + m * 16 + l16;
                int o   = ((lane >> 4) * 16 + kk * 64) ^ ((row & 7) << 4);
                af[m] = *reinterpret_cast<const bf16x8*>((const char*)&As[0][0] + row * 128 + o);
            }
#pragma unroll
            for (int n = 0; n < 4; ++n) {
                int row = wc * 64 + n * 16 + l16;
                int o   = ((lane >> 4) * 16 + kk * 64) ^ ((row & 7) << 4);
                bf_[n] = *reinterpret_cast<const bf16x8*>((const char*)&Bs[0][0] + row * 128 + o);
            }
#pragma unroll
            for (int m = 0; m < 4; ++m)
#pragma unroll
                for (int n = 0; n < 4; ++n)
                    acc[m][n] = __builtin_amdgcn_mfma_f32_16x16x32_bf16(
                        af[m], bf_[n], acc[m][n], 0, 0, 0);
        }
    }

    int crow = row0 + wr * 64;
    int ccol = col0 + wc * 64;
#pragma unroll
    for (int n = 0; n < 4; ++n) {
        int col = ccol + n * 16 + l16;
        float b = bias[col];
#pragma unroll
        for (int m = 0; m < 4; ++m) {
            int r = crow + m * 16 + (lane >> 4) * 4;
#pragma unroll
            for (int q = 0; q < 4; ++q)
                out[(size_t)(r + q) * D_MODEL + col] = acc[m][n][q] + b;
        }
    }
}

// ---------- launch ----------

extern "C" void kernel_launch(void* const* d_in, const int* in_sizes, int n_in,
                              void* d_out, int out_size, void* d_ws, size_t ws_size,
                              hipStream_t stream) {
    const float* x    = (const float*)d_in[0];
    const float* w    = (const float*)d_in[1];
    const float* bias = (const float*)d_in[2];
    float* out        = (float*)d_out;
    const int N       = in_sizes[0] / D_MODEL;   // 32768

    char* ws               = (char*)d_ws;
    unsigned*       ma_u   = (unsigned*)(ws);
    unsigned*       mw_u   = (unsigned*)(ws + 4096);
    float*          s      = (float*)(ws + 8192);
    unsigned short* Wp     = (unsigned short*)(ws + 16384);
    unsigned short* Xb     = (unsigned short*)(ws + 16384 + (size_t)D_MODEL * D_MODEL * 2);
    const int nPart        = N / CC_ROWS;   // 2048
    float*          part   = (float*)(ws + 16384 + (size_t)D_MODEL * D_MODEL * 2
                                               + (size_t)N * D_MODEL * 2);

    size_t need = 16384 + (size_t)D_MODEL * D_MODEL * 2 + (size_t)N * D_MODEL * 2
                + (size_t)nPart * D_MODEL * 4;
    bool preconv = ws_size >= need;

    init_u32<<<8, 256, 0, stream>>>((unsigned*)ws, 2048);

    if (preconv) {
        colmax_convert<<<nPart, 256, 0, stream>>>(x, part, Xb);
        reduce_partial<<<dim3(D_MODEL / 256, nPart / 64), 256, 0, stream>>>(part, ma_u);
    } else {
        colmax_kernel<<<dim3(D_MODEL / 256, 64), 256, 0, stream>>>(x, N / 64, D_MODEL, ma_u);
    }
    colmax_kernel<<<dim3(D_MODEL / 256, 16), 256, 0, stream>>>(w, D_MODEL / 16, D_MODEL, mw_u);
    scale_kernel<<<D_MODEL / 256, 256, 0, stream>>>(ma_u, mw_u, s);
    build_w_kernel<<<D_MODEL, 256, 0, stream>>>(w, s, Wp);

    if (preconv) {
        int nblk = (N / GBM) * (D_MODEL / GBN);   // 512
        gemm_main<<<nblk, 512, 0, stream>>>(Xb, Wp, bias, out);
    } else {
        int nblk = (N / 128) * (D_MODEL / 128);
        gemm_fallback<<<nblk, 256, 0, stream>>>(x, Wp, bias, out, N);
    }
}

// Round 9
// 153.982 us; speedup vs baseline: 1.1094x; 1.0423x over previous
//
#include <hip/hip_runtime.h>
#include <hip/hip_bf16.h>
#include <stdint.h>

#define D_MODEL 1024

typedef __attribute__((ext_vector_type(4))) float  f32x4;
typedef __attribute__((ext_vector_type(8))) __bf16 bf16x8;
typedef __attribute__((ext_vector_type(8))) unsigned short u16x8;
typedef __attribute__((ext_vector_type(4))) unsigned short u16x4;

// ---------- helpers ----------

__device__ __forceinline__ unsigned order_map(float x) {
    unsigned u = __float_as_uint(x);
    return (u & 0x80000000u) ? ~u : (u | 0x80000000u);
}
__device__ __forceinline__ float order_unmap(unsigned m) {
    unsigned b = (m & 0x80000000u) ? (m & 0x7fffffffu) : ~m;
    return __uint_as_float(b);
}
__device__ __forceinline__ unsigned short f2bf(float f) {
    unsigned u = __float_as_uint(f);
    u += 0x7fffu + ((u >> 16) & 1u);
    return (unsigned short)(u >> 16);
}

// ---------- prelude kernels (unchanged — at BW floor) ----------

__global__ void init_u32(unsigned* __restrict__ p, int n) {
    int i = blockIdx.x * blockDim.x + threadIdx.x;
    if (i < n) p[i] = 0u;
}

__global__ void colmax_kernel(const float* __restrict__ src, int rows_per_slab,
                              int cols, unsigned* __restrict__ out_u) {
    int k = blockIdx.x * blockDim.x + threadIdx.x;
    const float* p = src + (size_t)blockIdx.y * rows_per_slab * cols + k;
    float m = -__builtin_inff();
#pragma unroll 4
    for (int r = 0; r < rows_per_slab; ++r)
        m = fmaxf(m, p[(size_t)r * cols]);
    atomicMax(&out_u[k], order_map(m));
}

#define CC_ROWS 16
__global__ __launch_bounds__(256)
void colmax_convert(const float* __restrict__ x,
                    float* __restrict__ partial,
                    unsigned short* __restrict__ xb) {
    int c4 = threadIdx.x * 4;
    size_t base = (size_t)blockIdx.x * CC_ROWS * D_MODEL + c4;
    f32x4 m4 = {-__builtin_inff(), -__builtin_inff(), -__builtin_inff(), -__builtin_inff()};
#pragma unroll 8
    for (int r = 0; r < CC_ROWS; ++r) {
        f32x4 v = *reinterpret_cast<const f32x4*>(&x[base + (size_t)r * D_MODEL]);
        u16x4 o;
#pragma unroll
        for (int e = 0; e < 4; ++e) { m4[e] = fmaxf(m4[e], v[e]); o[e] = f2bf(v[e]); }
        *reinterpret_cast<u16x4*>(&xb[base + (size_t)r * D_MODEL]) = o;
    }
    *reinterpret_cast<f32x4*>(&partial[(size_t)blockIdx.x * D_MODEL + c4]) = m4;
}

__global__ void reduce_partial(const float* __restrict__ partial,
                               unsigned* __restrict__ ma_u) {
    int col  = blockIdx.x * 256 + threadIdx.x;
    int b0   = blockIdx.y * 64;
    float m = -__builtin_inff();
#pragma unroll 8
    for (int i = 0; i < 64; ++i)
        m = fmaxf(m, partial[(size_t)(b0 + i) * D_MODEL + col]);
    atomicMax(&ma_u[col], order_map(m));
}

__global__ void scale_kernel(const unsigned* __restrict__ ma_u,
                             const unsigned* __restrict__ mw_u,
                             float* __restrict__ s) {
    int k = blockIdx.x * blockDim.x + threadIdx.x;
    if (k < D_MODEL) {
        float ma = order_unmap(ma_u[k]);
        float mw = order_unmap(mw_u[k]);
        s[k] = sqrtf(ma) / sqrtf(mw);   // ALPHA = 0.5
    }
}

__global__ void build_w_kernel(const float* __restrict__ W, const float* __restrict__ s,
                               unsigned short* __restrict__ Wp) {
    int j  = blockIdx.x;
    int k4 = threadIdx.x * 4;
    float sj = s[j];
    f32x4 w  = *reinterpret_cast<const f32x4*>(&W[(size_t)j * D_MODEL + k4]);
    f32x4 sk = *reinterpret_cast<const f32x4*>(&s[k4]);
    u16x4 o;
#pragma unroll
    for (int i = 0; i < 4; ++i) o[i] = f2bf(sj * w[i] / sk[i]);
    *reinterpret_cast<u16x4*>(&Wp[(size_t)j * D_MODEL + k4]) = o;
}

// ---------- GEMM: 256x256 tile, 8 waves (2Mx4N), BK=32, TRIPLE buffer ----------
// R9 change: 3 LDS buffers + counted vmcnt. stage(t+2) issued during tile t ->
// 2-tile issue-to-use slack (~5000 cyc >> L2 latency) -> steady-state vmcnt(4)
// returns instantly; the per-tile vmcnt(0) drain (the R5-R8 invariant stall)
// is eliminated. One barrier per tile. Per wave per tile: 12 ds_read_b128 +
// 32 independent MFMAs (1 per acc -> no chains).
// LDS layout: 2 rows packed per 128B line; slot-XOR swizzle (both-sides, #21).
#define GBM 256
#define GBN 256
#define GBK 32
#define GNT (D_MODEL / GBK)   // 32
#define BUF_SHORTS 8192       // 16 KB per matrix per buffer

__global__ __launch_bounds__(512, 2)
void gemm_main(const unsigned short* __restrict__ Xb,
               const unsigned short* __restrict__ Wp,
               const float* __restrict__ bias,
               float* __restrict__ out) {
    // [3 bufs A][3 bufs B], 96 KB total
    __shared__ __align__(16) unsigned short lds[6 * BUF_SHORTS];

    int flat  = blockIdx.x;
    int xcd   = flat & 7;
    int j     = flat >> 3;                      // 0..63
    int col0  = (j & 3) * GBN;                  // 4 col panels
    int row0  = ((xcd << 4) + (j >> 2)) * GBM;  // chunk 0..127 (within-XCD reuse)

    int tid  = threadIdx.x;
    int wave = tid >> 6;
    int lane = tid & 63;
    int wr   = wave >> 2;      // 0..1 : rows wr*128
    int wc   = wave & 3;       // 0..3 : cols wc*64
    int l16  = lane & 15;
    int lq   = lane >> 4;      // 0..3 : k-quarter (8 bf16)

    // staging decomposition: line = 128B = 2 rows x 32 bf16... per round a wave
    // fills 8 lines; lane l -> line (l>>3), phys slot (l&7); content = logical
    // slot (l&7)^(l>>3)  [slot = (h<<2)|q : h=row parity, q=k-quarter]
    int sline = lane >> 3;                  // 0..7 within wave's 8-line group
    int slog  = (lane & 7) ^ sline;
    int sh    = slog >> 2;                  // row parity
    int sq    = slog & 3;                   // k-quarter

    f32x4 acc[8][4];
#pragma unroll
    for (int m = 0; m < 8; ++m)
#pragma unroll
        for (int n = 0; n < 4; ++n)
            acc[m][n] = (f32x4){0.f, 0.f, 0.f, 0.f};

    // stage tile t (A 16KB + B 16KB) into buffer b: 2 rounds x (1 A + 1 B) per wave
    auto stage = [&](int t, int b) {
        int k0 = t * GBK;
#pragma unroll
        for (int r = 0; r < 2; ++r) {
            int line = r * 64 + wave * 8 + sline;     // 0..127
            const unsigned short* gA =
                Xb + (size_t)(row0 + 2 * line + sh) * D_MODEL + k0 + sq * 8;
            __builtin_amdgcn_global_load_lds(
                (const __attribute__((address_space(1))) void*)gA,
                (__attribute__((address_space(3))) void*)&lds[b * BUF_SHORTS + line * 64],
                16, 0, 0);
            const unsigned short* gB =
                Wp + (size_t)(col0 + 2 * line + sh) * D_MODEL + k0 + sq * 8;
            __builtin_amdgcn_global_load_lds(
                (const __attribute__((address_space(1))) void*)gB,
                (__attribute__((address_space(3))) void*)&lds[(3 + b) * BUF_SHORTS + line * 64],
                16, 0, 0);
        }
    };

    // prologue: tiles 0,1 (one-time latency; steady state has 2-tile slack)
    stage(0, 0);
    stage(1, 1);

    int cur = 0;   // t % 3
#pragma unroll 1
    for (int t = 0; t < GNT; ++t) {
        // wait: everything up to tile t landed. Outstanding newer: stage(t+1)=4.
        if (t + 1 < GNT) asm volatile("s_waitcnt vmcnt(4)" ::: "memory");
        else             asm volatile("s_waitcnt vmcnt(0)" ::: "memory");
        __builtin_amdgcn_s_barrier();   // all waves done with buf[(t+2)%3]'s old tile

        if (t + 2 < GNT) {
            int bnext = cur >= 1 ? cur - 1 : cur + 2;   // (t+2)%3
            stage(t + 2, bnext);
        }

        const char* Ab = (const char*)&lds[cur * BUF_SHORTS];
        const char* Bb = (const char*)&lds[(3 + cur) * BUF_SHORTS];

        // B frags: cols wc*64 + n*16 + l16, k-quarter lq
        bf16x8 bfr[4];
#pragma unroll
        for (int n = 0; n < 4; ++n) {
            int cc   = wc * 64 + n * 16 + l16;
            int line = cc >> 1;
            int o    = (((cc & 1) << 6) + (lq << 4)) ^ ((line & 7) << 4);
            bfr[n] = *reinterpret_cast<const bf16x8*>(Bb + line * 128 + o);
        }
        // A frags: rows wr*128 + m*16 + l16
        bf16x8 afr[8];
#pragma unroll
        for (int m = 0; m < 8; ++m) {
            int rr   = wr * 128 + m * 16 + l16;
            int line = rr >> 1;
            int o    = (((rr & 1) << 6) + (lq << 4)) ^ ((line & 7) << 4);
            afr[m] = *reinterpret_cast<const bf16x8*>(Ab + line * 128 + o);
        }

        __builtin_amdgcn_s_setprio(1);
#pragma unroll
        for (int m = 0; m < 8; ++m)
#pragma unroll
            for (int n = 0; n < 4; ++n)
                acc[m][n] = __builtin_amdgcn_mfma_f32_16x16x32_bf16(
                    afr[m], bfr[n], acc[m][n], 0, 0, 0);
        __builtin_amdgcn_s_setprio(0);

        cur = cur == 2 ? 0 : cur + 1;
    }

    // ---- epilogue: C/D col = lane&15, row = lq*4 + q ----
    int crow = row0 + wr * 128;
    int ccol = col0 + wc * 64;
#pragma unroll
    for (int n = 0; n < 4; ++n) {
        int col = ccol + n * 16 + l16;
        float b = bias[col];
#pragma unroll
        for (int m = 0; m < 8; ++m) {
            int r = crow + m * 16 + lq * 4;
#pragma unroll
            for (int q = 0; q < 4; ++q)
                out[(size_t)(r + q) * D_MODEL + col] = acc[m][n][q] + b;
        }
    }
}

// fallback (ws too small for Xb): reg-staged f32->bf16, single buffer 128x128
__global__ __launch_bounds__(256)
void gemm_fallback(const float* __restrict__ X, const unsigned short* __restrict__ Wp,
                   const float* __restrict__ bias, float* __restrict__ out, int N) {
    __shared__ __align__(16) unsigned short As[128][64];
    __shared__ __align__(16) unsigned short Bs[128][64];

    int flat = blockIdx.x;
    int swz  = ((gridDim.x & 7) == 0)
             ? (flat & 7) * (gridDim.x >> 3) + (flat >> 3) : flat;
    const int nColBlk = D_MODEL / 128;
    int row0 = (swz / nColBlk) * 128;
    int col0 = (swz % nColBlk) * 128;

    int tid  = threadIdx.x;
    int wave = tid >> 6;
    int lane = tid & 63;
    int wr   = wave >> 1;
    int wc   = wave & 1;
    int l16  = lane & 15;
    int srow  = lane >> 3;
    int skoff = ((lane & 7) ^ srow) << 3;

    f32x4 acc[4][4];
#pragma unroll
    for (int m = 0; m < 4; ++m)
#pragma unroll
        for (int n = 0; n < 4; ++n)
            acc[m][n] = (f32x4){0.f, 0.f, 0.f, 0.f};

    for (int k0 = 0; k0 < D_MODEL; k0 += 64) {
        __syncthreads();
#pragma unroll
        for (int i = 0; i < 4; ++i) {
            int c   = i * 256 + tid;
            int r   = c >> 3;
            int seg = c & 7;
            const float* gp = X + (size_t)(row0 + r) * D_MODEL + k0 + seg * 8;
            f32x4 x0 = *reinterpret_cast<const f32x4*>(gp);
            f32x4 x1 = *reinterpret_cast<const f32x4*>(gp + 4);
            u16x8 v;
#pragma unroll
            for (int e = 0; e < 4; ++e) { v[e] = f2bf(x0[e]); v[e + 4] = f2bf(x1[e]); }
            int off = (seg * 16) ^ ((r & 7) << 4);
            *reinterpret_cast<u16x8*>((char*)&As[0][0] + r * 128 + off) = v;
        }
#pragma unroll
        for (int i = 0; i < 4; ++i) {
            int r0 = (wave * 4 + i) * 8;
            const unsigned short* g = Wp + (size_t)(col0 + r0 + srow) * D_MODEL + k0 + skoff;
            __builtin_amdgcn_global_load_lds(
                (const __attribute__((address_space(1))) void*)g,
                (__attribute__((address_space(3))) void*)&Bs[r0][0], 16, 0, 0);
        }
        __syncthreads();
#pragma unroll
        for (int kk = 0; kk < 2; ++kk) {
            bf16x8 af[4], bf_[4];
#pragma unroll
            for (int m = 0; m < 4; ++m) {
                int row = wr * 64 + m * 16 + l16;
                int o   = ((lane >> 4) * 16 + kk * 64) ^ ((row & 7) << 4);
                af[m] = *reinterpret_cast<const bf16x8*>((const char*)&As[0][0] + row * 128 + o);
            }
#pragma unroll
            for (int n = 0; n < 4; ++n) {
                int row = wc * 64 + n * 16 + l16;
                int o   = ((lane >> 4) * 16 + kk * 64) ^ ((row & 7) << 4);
                bf_[n] = *reinterpret_cast<const bf16x8*>((const char*)&Bs[0][0] + row * 128 + o);
            }
#pragma unroll
            for (int m = 0; m < 4; ++m)
#pragma unroll
                for (int n = 0; n < 4; ++n)
                    acc[m][n] = __builtin_amdgcn_mfma_f32_16x16x32_bf16(
                        af[m], bf_[n], acc[m][n], 0, 0, 0);
        }
    }

    int crow = row0 + wr * 64;
    int ccol = col0 + wc * 64;
#pragma unroll
    for (int n = 0; n < 4; ++n) {
        int col = ccol + n * 16 + l16;
        float b = bias[col];
#pragma unroll
        for (int m = 0; m < 4; ++m) {
            int r = crow + m * 16 + (lane >> 4) * 4;
#pragma unroll
            for (int q = 0; q < 4; ++q)
                out[(size_t)(r + q) * D_MODEL + col] = acc[m][n][q] + b;
        }
    }
}

// ---------- launch ----------

extern "C" void kernel_launch(void* const* d_in, const int* in_sizes, int n_in,
                              void* d_out, int out_size, void* d_ws, size_t ws_size,
                              hipStream_t stream) {
    const float* x    = (const float*)d_in[0];
    const float* w    = (const float*)d_in[1];
    const float* bias = (const float*)d_in[2];
    float* out        = (float*)d_out;
    const int N       = in_sizes[0] / D_MODEL;   // 32768

    char* ws               = (char*)d_ws;
    unsigned*       ma_u   = (unsigned*)(ws);
    unsigned*       mw_u   = (unsigned*)(ws + 4096);
    float*          s      = (float*)(ws + 8192);
    unsigned short* Wp     = (unsigned short*)(ws + 16384);
    unsigned short* Xb     = (unsigned short*)(ws + 16384 + (size_t)D_MODEL * D_MODEL * 2);
    const int nPart        = N / CC_ROWS;   // 2048
    float*          part   = (float*)(ws + 16384 + (size_t)D_MODEL * D_MODEL * 2
                                               + (size_t)N * D_MODEL * 2);

    size_t need = 16384 + (size_t)D_MODEL * D_MODEL * 2 + (size_t)N * D_MODEL * 2
                + (size_t)nPart * D_MODEL * 4;
    bool preconv = ws_size >= need;

    init_u32<<<8, 256, 0, stream>>>((unsigned*)ws, 2048);

    if (preconv) {
        colmax_convert<<<nPart, 256, 0, stream>>>(x, part, Xb);
        reduce_partial<<<dim3(D_MODEL / 256, nPart / 64), 256, 0, stream>>>(part, ma_u);
    } else {
        colmax_kernel<<<dim3(D_MODEL / 256, 64), 256, 0, stream>>>(x, N / 64, D_MODEL, ma_u);
    }
    colmax_kernel<<<dim3(D_MODEL / 256, 16), 256, 0, stream>>>(w, D_MODEL / 16, D_MODEL, mw_u);
    scale_kernel<<<D_MODEL / 256, 256, 0, stream>>>(ma_u, mw_u, s);
    build_w_kernel<<<D_MODEL, 256, 0, stream>>>(w, s, Wp);

    if (preconv) {
        int nblk = (N / GBM) * (D_MODEL / GBN);   // 512
        gemm_main<<<nblk, 512, 0, stream>>>(Xb, Wp, bias, out);
    } else {
        int nblk = (N / 128) * (D_MODEL / 128);
        gemm_fallback<<<nblk, 256, 0, stream>>>(x, Wp, bias, out, N);
    }
}